// Round 7
// baseline (636.957 us; speedup 1.0000x reference)
//
#include <hip/hip_runtime.h>
#include <hip/hip_fp16.h>
#include <stdint.h>
#include <stddef.h>

// LSTM B=512,T=128,D=256,H=256,C=128, gates (i,j,f,o), FORGET_BIAS=1.
// R17 = R13's lstm_rec body (proven sound: __syncthreads, 104 VGPR) with
// R11's grid decomposition (512 blocks x 1 row) and NO launch-bounds cap:
//   R11 failed ONLY because LB(512,4) capped regs at 128 -> wreg[16] spilled
//   (VGPR=64, 2.27GB scratch writes). R13 runs at VGPR_Count=104, so TWO
//   512-thread blocks/CU fit in hardware under LB(512,2): 4 waves/SIMD x
//   104 = 416 <= 512 regs, LDS 2x17408 <= 160KB. Grid 512 -> 2 co-resident
//   INDEPENDENT blocks per CU; one block's VALU/epilogue phase overlaps the
//   other's MFMA phase (the 2.2k-cycle lockstep slack measured in R1).
//   Row is replicated to m-rows 0/4/8/12 (existing 4*quad publish), z-select
//   is block-uniform sel=R&3 (quad-dup addresses broadcast-coalesce), XCD
//   swizzle colocates the 4 sibling blocks sharing each packed z-uint2.
//   xproj/shuffle_w identical to R15.

typedef __attribute__((ext_vector_type(8))) __bf16 bf16x8;
typedef __attribute__((ext_vector_type(4))) __bf16 bf16x4;
typedef __attribute__((ext_vector_type(4))) float  f32x4;
typedef __attribute__((ext_vector_type(8))) int    i32x8;

#define LDH   264          // bf16 row stride (xproj A-tile, out staging)
#define LDF   272          // fp8 Ht row stride in bytes (256 + 16)
#define ZPS   2097152ull   // Zx plane stride in uint2 (32*128*8*64)
#define SONE  0x7F7F7F7F   // E8M0 unit scales (all blocks = 2^0)

__device__ __forceinline__ f32x4 mfma_bf16(bf16x8 a, bf16x8 b, f32x4 c) {
    return __builtin_amdgcn_mfma_f32_16x16x32_bf16(a, b, c, 0, 0, 0);
}
#define EXP2(x) __builtin_amdgcn_exp2f(x)
#define RCP(x)  __builtin_amdgcn_rcpf(x)
#define L2E  1.442695040f
#define L2E2 2.885390082f

// ---------------- 1) weight shuffle ----------------
__global__ __launch_bounds__(256) void shuffle_w(const float* __restrict__ Wk,
                                                 __bf16* __restrict__ WxF,
                                                 unsigned char* __restrict__ WhF) {
    int id = blockIdx.x * 256 + threadIdx.x;
    if (id < 32768) {                                  // Wx part (rows 0..255)
        int lane = id & 63, kt = (id >> 6) & 7, nt = id >> 9;
        int quad = lane >> 4, l16 = lane & 15;
        const float* src = Wk + (size_t)(kt * 32 + quad * 8) * 1024 + nt * 16 + l16;
        __bf16* dst = WxF + ((size_t)(nt * 8 + kt) * 64 + lane) * 8;
#pragma unroll
        for (int j = 0; j < 8; ++j) dst[j] = (__bf16)src[(size_t)j * 1024];
    } else if (id < 40960) {                           // Wh part (rows 256..511)
        int i = id - 32768;
        int lane = i & 63, kt = (i >> 6) & 1, ng = i >> 7;
        int n = ng * 16 + (lane & 15);
        int kb = 256 + kt * 128 + (lane >> 4) * 32;
        int* dst = (int*)(WhF + (((size_t)ng * 2 + kt) * 64 + lane) * 32);
#pragma unroll
        for (int d = 0; d < 8; ++d) {
            float w0 = Wk[(size_t)(kb + 4 * d + 0) * 1024 + n];
            float w1 = Wk[(size_t)(kb + 4 * d + 1) * 1024 + n];
            float w2 = Wk[(size_t)(kb + 4 * d + 2) * 1024 + n];
            float w3 = Wk[(size_t)(kb + 4 * d + 3) * 1024 + n];
            int lo = __builtin_amdgcn_cvt_pk_fp8_f32(w0, w1, 0, false);
            dst[d]  = __builtin_amdgcn_cvt_pk_fp8_f32(w2, w3, lo, true);
        }
    }
}

// ---------------- 2) x-projection: M=32/block, as R15 ----------------
__global__ __launch_bounds__(512, 4) void xproj(const float* __restrict__ x,
        const __bf16* __restrict__ WxF, const float* __restrict__ bias,
        uint2* __restrict__ Zx) {
    __shared__ __attribute__((aligned(16))) __bf16 At[32 * LDH];
    const int tid = threadIdx.x, wv = tid >> 6, lane = tid & 63;
    const int l16 = lane & 15, quad = lane >> 4;
    const int rb = blockIdx.x & 31, tg = blockIdx.x >> 5;   // tg 0..63

#pragma unroll
    for (int rr = 0; rr < 4; ++rr) {
        int Arow = wv * 4 + rr;                  // 32 A-rows: [tt=Arow>>4][r=Arow&15]
        int tt = Arow >> 4, r = Arow & 15;
        const float4 xv = *((const float4*)(x + ((size_t)(rb * 16 + r) * 128 + tg * 2 + tt) * 256) + lane);
        bf16x4 xb = { (__bf16)xv.x, (__bf16)xv.y, (__bf16)xv.z, (__bf16)xv.w };
        *(bf16x4*)&At[Arow * LDH + lane * 4] = xb;
    }
    __syncthreads();

    f32x4 acc[2][8];
#pragma unroll
    for (int tt = 0; tt < 2; ++tt)
#pragma unroll
        for (int nt = 0; nt < 8; ++nt) acc[tt][nt] = (f32x4){0.f, 0.f, 0.f, 0.f};

#pragma unroll
    for (int kt = 0; kt < 8; ++kt) {
        bf16x8 af[2];
#pragma unroll
        for (int tt = 0; tt < 2; ++tt)
            af[tt] = *(const bf16x8*)&At[(tt * 16 + l16) * LDH + kt * 32 + quad * 8];
#pragma unroll
        for (int nt = 0; nt < 8; ++nt) {
            bf16x8 wf = *(const bf16x8*)&WxF[(((size_t)(wv * 8 + nt) * 8 + kt) * 64 + lane) * 8];
#pragma unroll
            for (int tt = 0; tt < 2; ++tt) acc[tt][nt] = mfma_bf16(af[tt], wf, acc[tt][nt]);
        }
    }

#pragma unroll
    for (int nt = 0; nt < 8; ++nt) {
        int col = wv * 128 + nt * 16 + l16;
        float bb = bias[col] + ((col >= 512 && col < 768) ? 1.0f : 0.0f);
#pragma unroll
        for (int tt = 0; tt < 2; ++tt) {
            int t = tg * 2 + tt;
            union { __half h[4]; uint2 u; } pk;
#pragma unroll
            for (int r = 0; r < 4; ++r) pk.h[r] = __float2half(acc[tt][nt][r] + bb);
            Zx[(size_t)wv * ZPS + ((size_t)(rb * 128 + t) * 8 + nt) * 64 + lane] = pk.u;
        }
    }
}

// ---------------- 3) recurrent loop: 512 blocks x 1 batch row ----------------
// R13 step body; only the z half-select changed from quad to the
// block-uniform SEL (one real row, replicated into m-rows 0/4/8/12).
#define LSTM_STEP(TT, ZR, ZZU, ZRE, ZZE, RBUF, WBUF)                           \
    {                                                                          \
        i32x8 afr[2];                                                          \
        _Pragma("unroll")                                                      \
        for (int kt = 0; kt < 2; ++kt) {                                       \
            const uint4* ap = (const uint4*)&HtF[RBUF][l16 * LDF + kt * 128 + quad * 32]; \
            uint4 lo = ap[0], hi = ap[1];                                      \
            afr[kt] = (i32x8){(int)lo.x, (int)lo.y, (int)lo.z, (int)lo.w,      \
                              (int)hi.x, (int)hi.y, (int)hi.z, (int)hi.w};     \
        }                                                                      \
        f32x4 acc[8];                                                          \
        _Pragma("unroll")                                                      \
        for (int p = 0; p < 8; ++p) acc[p] = (f32x4){ZZU[p], 0.f, 0.f, 0.f};   \
        {                                                                      \
            int tl = ((TT) + 2 > 127) ? 127 : ((TT) + 2);                      \
            size_t zi = zi0 + (size_t)tl * 512;                                \
            _Pragma("unroll")                                                  \
            for (int p = 0; p < 8; ++p) ZR[p] = Zx[p * ZPS + zi];              \
        }                                                                      \
        __builtin_amdgcn_s_setprio(1);                                         \
        _Pragma("unroll")                                                      \
        for (int kt = 0; kt < 2; ++kt)                                         \
            _Pragma("unroll")                                                  \
            for (int p = 0; p < 8; ++p)                                        \
                acc[p] = __builtin_amdgcn_mfma_scale_f32_16x16x128_f8f6f4(     \
                    afr[kt], wreg[p * 2 + kt], acc[p], 0, 0, 0, SONE, 0, SONE);\
        __builtin_amdgcn_s_setprio(0);                                         \
        _Pragma("unroll")                                                      \
        for (int p = 0; p < 8; ++p) {                                          \
            unsigned w = (sel & 2) ? ZRE[p].y : ZRE[p].x;                      \
            w = (sel & 1) ? (w >> 16) : (w & 0xffff);                          \
            union { unsigned short u; __half h; } cv; cv.u = (unsigned short)w;\
            ZZE[p] = __half2float(cv.h);                                       \
        }                                                                      \
        unsigned char* ldsw = &HtF[WBUF][0];                                   \
        _Pragma("unroll")                                                      \
        for (int hf = 0; hf < 2; ++hf) {                                       \
            float iv = acc[0 + hf][0];                                         \
            float jv = acc[2 + hf][0];                                         \
            float fv = acc[4 + hf][0];                                         \
            float ov = acc[6 + hf][0];                                         \
            float si = RCP(1.f + EXP2(-L2E * iv));                             \
            float sf = RCP(1.f + EXP2(-L2E * fv));                             \
            float so = RCP(1.f + EXP2(-L2E * ov));                             \
            float tj = 2.f * RCP(1.f + EXP2(-L2E2 * jv)) - 1.f;                \
            float c = c_[hf] * sf + si * tj;                                   \
            c_[hf] = c;                                                        \
            float tc = 2.f * RCP(1.f + EXP2(-L2E2 * c)) - 1.f;                 \
            float h = tc * so;                                                 \
            hr[hf] = h;                                                        \
            unsigned pb = (unsigned)__builtin_amdgcn_cvt_pk_fp8_f32(h, h, 0, false); \
            ldsw[(4 * quad) * LDF + hf * 128 + col0] = (unsigned char)pb;      \
        }                                                                      \
        __syncthreads();   /* publish h(t+1) — architectural barrier */        \
    }

__global__ __launch_bounds__(512, 2) void lstm_rec(const unsigned char* __restrict__ WhF,
        const uint2* __restrict__ Zx, const float* __restrict__ wout,
        const float* __restrict__ bout, float* __restrict__ out) {
    // Ht: plain fp8 matrix [16 rows][272 B], double-buffered. The single
    // batch row is REPLICATED into m-rows 0,4,8,12 (each quad publishes its
    // copy); other rows stay zero (m-padding).
    __shared__ __attribute__((aligned(16))) unsigned char HtF[2][16 * LDF];
    __shared__ __attribute__((aligned(16))) __bf16 HtB[16 * LDH];   // out staging
    const int tid = threadIdx.x, wv = tid >> 6, lane = tid & 63;
    const int l16 = lane & 15, quad = lane >> 4;
    // XCD-colocating bijective swizzle (512 = 8 XCDs x 64): the 4 sibling
    // blocks sharing each packed z-uint2 (same R>>2) land on one XCD's L2.
    const int R = ((blockIdx.x & 7) << 6) | (blockIdx.x >> 3);  // batch row
    const int sel = R & 3;                   // half-select inside z uint2 (uniform)

    // Wh MX B-frags: 16 x v8i32 = 128 regs (p = g*2+hf, kt128 = 0,1)
    i32x8 wreg[16];
#pragma unroll
    for (int p = 0; p < 8; ++p) {
        int ng = (p >> 1) * 16 + (p & 1) * 8 + wv;   // cols g*256+hf*128+wv*16+l16
#pragma unroll
        for (int kt = 0; kt < 2; ++kt) {
            const uint4* wp = (const uint4*)(WhF + (((size_t)ng * 2 + kt) * 64 + lane) * 32);
            uint4 lo = wp[0], hi = wp[1];
            wreg[p * 2 + kt] = (i32x8){(int)lo.x, (int)lo.y, (int)lo.z, (int)lo.w,
                                       (int)hi.x, (int)hi.y, (int)hi.z, (int)hi.w};
        }
    }
    for (int i = tid; i < (16 * LDF * 2) / 4; i += 512) ((uint*)HtF[0])[i] = 0u;

    const int col0 = wv * 16 + l16;
    float c_[2] = {0.f, 0.f};
    float hr[2] = {0.f, 0.f};
    // z uint2 for row R: lane' = ((R>>2)&3)*16 + l16 of 16-row group R>>4,
    // plane p, half #sel. Quad-independent address -> broadcast coalescing.
    const size_t zi0 = ((size_t)(R >> 4) * 1024 + wv) * 64
                     + (size_t)((R >> 2) & 3) * 16 + l16;

    // raw ping-pong (uint2) + extracted-float ping-pong
    uint2 zrA[8], zrB[8];
    float zzA[8], zzB[8];
#pragma unroll
    for (int p = 0; p < 8; ++p) zrA[p] = Zx[p * ZPS + zi0];
#pragma unroll
    for (int p = 0; p < 8; ++p) zrB[p] = Zx[p * ZPS + zi0 + 512];
#pragma unroll
    for (int p = 0; p < 8; ++p) {            // pre-extract z(0) -> zzA
        unsigned w = (sel & 2) ? zrA[p].y : zrA[p].x;
        w = (sel & 1) ? (w >> 16) : (w & 0xffff);
        union { unsigned short u; __half h; } cv; cv.u = (unsigned short)w;
        zzA[p] = __half2float(cv.h);
    }
    __syncthreads();                         // HtF zero-init visible

#pragma unroll 1
    for (int t = 0; t < 128; t += 2) {
        // even: use zzA, reload zrA <- z(t+2), extract zrB(z(t+1)) -> zzB
        LSTM_STEP(t,     zrA, zzA, zrB, zzB, 0, 1);
        // odd:  use zzB, reload zrB <- z(t+3), extract zrA(z(t+2)) -> zzA
        LSTM_STEP(t + 1, zrB, zzB, zrA, zzA, 1, 0);
    }

    // ---- output projection: fp32 h -> bf16 staging tile -> MFMA ----
    for (int i = tid; i < 16 * LDH; i += 512) HtB[i] = (__bf16)0.f;
    __syncthreads();
#pragma unroll
    for (int hf = 0; hf < 2; ++hf)
        HtB[(4 * quad) * LDH + hf * 128 + col0] = (__bf16)hr[hf];
    __syncthreads();

    bf16x8 wo[8];
#pragma unroll
    for (int kt = 0; kt < 8; ++kt) {
        bf16x8 f;
#pragma unroll
        for (int j = 0; j < 8; ++j)
            f[j] = (__bf16)wout[(size_t)(kt * 32 + quad * 8 + j) * 128 + col0];
        wo[kt] = f;
    }
    f32x4 oa = {0.f, 0.f, 0.f, 0.f};
#pragma unroll
    for (int kt = 0; kt < 8; ++kt) {
        bf16x8 af = *(const bf16x8*)&HtB[l16 * LDH + kt * 32 + quad * 8];
        oa = mfma_bf16(af, wo[kt], oa);
    }
    if (quad == 0)                            // all quads hold identical oa[0]
        out[(size_t)R * 128 + col0] = oa[0] + bout[col0];
}

extern "C" void kernel_launch(void* const* d_in, const int* in_sizes, int n_in,
                              void* d_out, int out_size, void* d_ws, size_t ws_size,
                              hipStream_t stream) {
    const float* x    = (const float*)d_in[0];
    const float* Wk   = (const float*)d_in[1];
    const float* bias = (const float*)d_in[2];
    const float* wout = (const float*)d_in[3];
    const float* bout = (const float*)d_in[4];
    float* out = (float*)d_out;

    __bf16*        WxF = (__bf16*)d_ws;                      // 512 KB
    unsigned char* WhF = (unsigned char*)d_ws + 524288;      // 256 KB (fp8 MX frags)
    uint2*         Zx  = (uint2*)((char*)d_ws + 2097152);    // 128 MB, 8 planes

    shuffle_w<<<160, 256, 0, stream>>>(Wk, WxF, WhF);
    xproj<<<2048, 512, 0, stream>>>(x, WxF, bias, Zx);
    lstm_rec<<<512, 512, 0, stream>>>(WhF, Zx, wout, bout, out);
}

// Round 8
// 432.623 us; speedup vs baseline: 1.4723x; 1.4723x over previous
//
#include <hip/hip_runtime.h>
#include <hip/hip_fp16.h>
#include <stdint.h>
#include <stddef.h>

// LSTM B=512,T=128,D=256,H=256,C=128, gates (i,j,f,o), FORGET_BIAS=1.
// R18 = R15's lstm_rec (proven 241us) + xproj rewritten as a proper
// 128x128-tile GEMM (m93 structure: 4 waves, 4x4 16x16x32 frags/wave,
// BK=32 double-buffered LDS A-staging with fp32->bf16 cvt, B-frags from
// L2-resident WxF, grid 4096, LB(256,2) -> >=2 blocks/CU, no reg cap trap).
// M-tile = 16 batch x 8 t so the epilogue emits the EXACT verified Zx
// uint2 packing (4 consecutive b per lane at fixed t).
// R17 lesson: lstm_rec co-residency retired (2 blocks/CU gave ZERO overlap
// + 744MB scratch writes; per-CU util identical to R13 at 2x the time).

typedef __attribute__((ext_vector_type(8))) __bf16 bf16x8;
typedef __attribute__((ext_vector_type(4))) __bf16 bf16x4;
typedef __attribute__((ext_vector_type(4))) float  f32x4;
typedef __attribute__((ext_vector_type(8))) int    i32x8;

#define LDH   264          // bf16 row stride (out staging in lstm_rec)
#define LDF   272          // fp8 Ht row stride in bytes (256 + 16)
#define ZPS   2097152ull   // Zx plane stride in uint2 (32*128*8*64)
#define SONE  0x7F7F7F7F   // E8M0 unit scales (all blocks = 2^0)
#define LDA   36           // xproj A-tile row stride in bf16 (32 + 4 pad)

__device__ __forceinline__ f32x4 mfma_bf16(bf16x8 a, bf16x8 b, f32x4 c) {
    return __builtin_amdgcn_mfma_f32_16x16x32_bf16(a, b, c, 0, 0, 0);
}
#define EXP2(x) __builtin_amdgcn_exp2f(x)
#define RCP(x)  __builtin_amdgcn_rcpf(x)
#define L2E  1.442695040f
#define L2E2 2.885390082f

// ---------------- 1) weight shuffle ----------------
__global__ __launch_bounds__(256) void shuffle_w(const float* __restrict__ Wk,
                                                 __bf16* __restrict__ WxF,
                                                 unsigned char* __restrict__ WhF) {
    int id = blockIdx.x * 256 + threadIdx.x;
    if (id < 32768) {                                  // Wx part (rows 0..255)
        int lane = id & 63, kt = (id >> 6) & 7, nt = id >> 9;
        int quad = lane >> 4, l16 = lane & 15;
        const float* src = Wk + (size_t)(kt * 32 + quad * 8) * 1024 + nt * 16 + l16;
        __bf16* dst = WxF + ((size_t)(nt * 8 + kt) * 64 + lane) * 8;
#pragma unroll
        for (int j = 0; j < 8; ++j) dst[j] = (__bf16)src[(size_t)j * 1024];
    } else if (id < 40960) {                           // Wh part (rows 256..511)
        int i = id - 32768;
        int lane = i & 63, kt = (i >> 6) & 1, ng = i >> 7;
        int n = ng * 16 + (lane & 15);
        int kb = 256 + kt * 128 + (lane >> 4) * 32;
        int* dst = (int*)(WhF + (((size_t)ng * 2 + kt) * 64 + lane) * 32);
#pragma unroll
        for (int d = 0; d < 8; ++d) {
            float w0 = Wk[(size_t)(kb + 4 * d + 0) * 1024 + n];
            float w1 = Wk[(size_t)(kb + 4 * d + 1) * 1024 + n];
            float w2 = Wk[(size_t)(kb + 4 * d + 2) * 1024 + n];
            float w3 = Wk[(size_t)(kb + 4 * d + 3) * 1024 + n];
            int lo = __builtin_amdgcn_cvt_pk_fp8_f32(w0, w1, 0, false);
            dst[d]  = __builtin_amdgcn_cvt_pk_fp8_f32(w2, w3, lo, true);
        }
    }
}

// ---------------- 2) x-projection: 128x128-tile GEMM ----------------
// Grid 4096: p = blk&7 (N-tile == Zx plane), bt = blk>>3: bb = bt&31 (16 b),
// tg = bt>>5 (8 t). M-row m (0..127): b = bb*16 + (m&15), t = tg*8 + (m>>4).
// 4 waves (wm = w>>1 M-half, wn = w&1 N-half), 4x4 acc frags per wave.
// K=256 in 8 BK=32 steps, A double-buffered in LDS, B straight from WxF(L2).
__global__ __launch_bounds__(256, 2) void xproj(const float* __restrict__ x,
        const __bf16* __restrict__ WxF, const float* __restrict__ bias,
        uint2* __restrict__ Zx) {
    __shared__ __attribute__((aligned(16))) __bf16 As[2][128 * LDA];
    const int tid = threadIdx.x, w = tid >> 6, lane = tid & 63;
    const int l16 = lane & 15, q = lane >> 4;
    const int p = blockIdx.x & 7, bt = blockIdx.x >> 3;
    const int bb = bt & 31, tg = bt >> 5;
    const int wm = w >> 1, wn = w & 1;

    // stage k-step 0: 128 rows x 32 k, 4 float4 per thread, cvt to bf16
    {
#pragma unroll
        for (int i = 0; i < 4; ++i) {
            int s = tid + i * 256, row = s >> 3, f4 = s & 7;
            int b = bb * 16 + (row & 15), t_ = tg * 8 + (row >> 4);
            float4 v = *((const float4*)(x + (size_t)(b * 128 + t_) * 256) + f4);
            bf16x4 c4 = {(__bf16)v.x, (__bf16)v.y, (__bf16)v.z, (__bf16)v.w};
            *(bf16x4*)&As[0][row * LDA + f4 * 4] = c4;
        }
    }
    __syncthreads();

    f32x4 acc[4][4];
#pragma unroll
    for (int tt = 0; tt < 4; ++tt)
#pragma unroll
        for (int nf = 0; nf < 4; ++nf) acc[tt][nf] = (f32x4){0.f, 0.f, 0.f, 0.f};

#pragma unroll
    for (int ks = 0; ks < 8; ++ks) {
        float4 nv[4];
        if (ks < 7) {                       // prefetch next K-slab into regs
#pragma unroll
            for (int i = 0; i < 4; ++i) {
                int s = tid + i * 256, row = s >> 3, f4 = s & 7;
                int b = bb * 16 + (row & 15), t_ = tg * 8 + (row >> 4);
                nv[i] = *((const float4*)(x + (size_t)(b * 128 + t_) * 256 + (size_t)(ks + 1) * 32) + f4);
            }
        }
        bf16x8 wf[4];
#pragma unroll
        for (int nf = 0; nf < 4; ++nf) {
            int ntF = p * 8 + wn * 4 + nf;
            wf[nf] = *(const bf16x8*)&WxF[(((size_t)ntF * 8 + ks) * 64 + lane) * 8];
        }
#pragma unroll
        for (int tt = 0; tt < 4; ++tt) {
            bf16x8 af = *(const bf16x8*)&As[ks & 1][(wm * 64 + tt * 16 + l16) * LDA + q * 8];
#pragma unroll
            for (int nf = 0; nf < 4; ++nf)
                acc[tt][nf] = mfma_bf16(af, wf[nf], acc[tt][nf]);
        }
        if (ks < 7) {                       // publish next slab (other buffer)
#pragma unroll
            for (int i = 0; i < 4; ++i) {
                int s = tid + i * 256, row = s >> 3, f4 = s & 7;
                bf16x4 c4 = {(__bf16)nv[i].x, (__bf16)nv[i].y, (__bf16)nv[i].z, (__bf16)nv[i].w};
                *(bf16x4*)&As[(ks + 1) & 1][row * LDA + f4 * 4] = c4;
            }
            __syncthreads();
        }
    }

    // epilogue: pack 4 b-rows (q*4+r) per lane into one Zx uint2 (fp16)
    const float fb = (p == 4 || p == 5) ? 1.0f : 0.0f;   // forget bias planes
#pragma unroll
    for (int nf = 0; nf < 4; ++nf) {
        int cnt = wn * 4 + nf;
        float bb_ = bias[p * 128 + cnt * 16 + l16] + fb;
#pragma unroll
        for (int tt = 0; tt < 4; ++tt) {
            int t_ = tg * 8 + wm * 4 + tt;
            union { __half h[4]; uint2 u; } pk;
#pragma unroll
            for (int r = 0; r < 4; ++r) pk.h[r] = __float2half(acc[tt][nf][r] + bb_);
            Zx[(size_t)p * ZPS + ((size_t)(bb * 128 + t_) * 8 + cnt) * 64 + q * 16 + l16] = pk.u;
        }
    }
}

// ---------------- 3) recurrent loop: 128 blocks x 4 batch rows ----------------
// BIT-IDENTICAL to R13/R15 (proven sound + 241us).
#define LSTM_STEP(TT, ZR, ZZU, ZRE, ZZE, RBUF, WBUF)                           \
    {                                                                          \
        i32x8 afr[2];                                                          \
        _Pragma("unroll")                                                      \
        for (int kt = 0; kt < 2; ++kt) {                                       \
            const uint4* ap = (const uint4*)&HtF[RBUF][l16 * LDF + kt * 128 + quad * 32]; \
            uint4 lo = ap[0], hi = ap[1];                                      \
            afr[kt] = (i32x8){(int)lo.x, (int)lo.y, (int)lo.z, (int)lo.w,      \
                              (int)hi.x, (int)hi.y, (int)hi.z, (int)hi.w};     \
        }                                                                      \
        f32x4 acc[8];                                                          \
        _Pragma("unroll")                                                      \
        for (int p = 0; p < 8; ++p) acc[p] = (f32x4){ZZU[p], 0.f, 0.f, 0.f};   \
        {                                                                      \
            int tl = ((TT) + 2 > 127) ? 127 : ((TT) + 2);                      \
            size_t zi = zi0 + (size_t)tl * 512;                                \
            _Pragma("unroll")                                                  \
            for (int p = 0; p < 8; ++p) ZR[p] = Zx[p * ZPS + zi];              \
        }                                                                      \
        __builtin_amdgcn_s_setprio(1);                                         \
        _Pragma("unroll")                                                      \
        for (int kt = 0; kt < 2; ++kt)                                         \
            _Pragma("unroll")                                                  \
            for (int p = 0; p < 8; ++p)                                        \
                acc[p] = __builtin_amdgcn_mfma_scale_f32_16x16x128_f8f6f4(     \
                    afr[kt], wreg[p * 2 + kt], acc[p], 0, 0, 0, SONE, 0, SONE);\
        __builtin_amdgcn_s_setprio(0);                                         \
        _Pragma("unroll")                                                      \
        for (int p = 0; p < 8; ++p) {                                          \
            unsigned w = (quad & 2) ? ZRE[p].y : ZRE[p].x;                     \
            w = (quad & 1) ? (w >> 16) : (w & 0xffff);                         \
            union { unsigned short u; __half h; } cv; cv.u = (unsigned short)w;\
            ZZE[p] = __half2float(cv.h);                                       \
        }                                                                      \
        unsigned char* ldsw = &HtF[WBUF][0];                                   \
        _Pragma("unroll")                                                      \
        for (int hf = 0; hf < 2; ++hf) {                                       \
            float iv = acc[0 + hf][0];                                         \
            float jv = acc[2 + hf][0];                                         \
            float fv = acc[4 + hf][0];                                         \
            float ov = acc[6 + hf][0];                                         \
            float si = RCP(1.f + EXP2(-L2E * iv));                             \
            float sf = RCP(1.f + EXP2(-L2E * fv));                             \
            float so = RCP(1.f + EXP2(-L2E * ov));                             \
            float tj = 2.f * RCP(1.f + EXP2(-L2E2 * jv)) - 1.f;                \
            float c = c_[hf] * sf + si * tj;                                   \
            c_[hf] = c;                                                        \
            float tc = 2.f * RCP(1.f + EXP2(-L2E2 * c)) - 1.f;                 \
            float h = tc * so;                                                 \
            hr[hf] = h;                                                        \
            unsigned pb = (unsigned)__builtin_amdgcn_cvt_pk_fp8_f32(h, h, 0, false); \
            ldsw[(4 * quad) * LDF + hf * 128 + col0] = (unsigned char)pb;      \
        }                                                                      \
        __syncthreads();   /* publish h(t+1) — architectural barrier */        \
    }

__global__ __launch_bounds__(512, 2) void lstm_rec(const unsigned char* __restrict__ WhF,
        const uint2* __restrict__ Zx, const float* __restrict__ wout,
        const float* __restrict__ bout, float* __restrict__ out) {
    __shared__ __attribute__((aligned(16))) unsigned char HtF[2][16 * LDF];
    __shared__ __attribute__((aligned(16))) __bf16 HtB[16 * LDH];   // out staging
    const int tid = threadIdx.x, wv = tid >> 6, lane = tid & 63;
    const int l16 = lane & 15, quad = lane >> 4;
    const int rbblk = blockIdx.x;            // batch rows 4*rbblk .. +3
    const int rb = rbblk >> 2, qb = rbblk & 3;

    // Wh MX B-frags: 16 x v8i32 = 128 regs (p = g*2+hf, kt128 = 0,1)
    i32x8 wreg[16];
#pragma unroll
    for (int p = 0; p < 8; ++p) {
        int ng = (p >> 1) * 16 + (p & 1) * 8 + wv;   // cols g*256+hf*128+wv*16+l16
#pragma unroll
        for (int kt = 0; kt < 2; ++kt) {
            const uint4* wp = (const uint4*)(WhF + (((size_t)ng * 2 + kt) * 64 + lane) * 32);
            uint4 lo = wp[0], hi = wp[1];
            wreg[p * 2 + kt] = (i32x8){(int)lo.x, (int)lo.y, (int)lo.z, (int)lo.w,
                                       (int)hi.x, (int)hi.y, (int)hi.z, (int)hi.w};
        }
    }
    for (int i = tid; i < (16 * LDF * 2) / 4; i += 512) ((uint*)HtF[0])[i] = 0u;

    const int col0 = wv * 16 + l16;
    float c_[2] = {0.f, 0.f};
    float hr[2] = {0.f, 0.f};
    const size_t zi0 = ((size_t)rb * 1024 + wv) * 64 + qb * 16 + l16;

    // raw ping-pong (uint2) + extracted-float ping-pong
    uint2 zrA[8], zrB[8];
    float zzA[8], zzB[8];
#pragma unroll
    for (int p = 0; p < 8; ++p) zrA[p] = Zx[p * ZPS + zi0];
#pragma unroll
    for (int p = 0; p < 8; ++p) zrB[p] = Zx[p * ZPS + zi0 + 512];
#pragma unroll
    for (int p = 0; p < 8; ++p) {            // pre-extract z(0) -> zzA
        unsigned w = (quad & 2) ? zrA[p].y : zrA[p].x;
        w = (quad & 1) ? (w >> 16) : (w & 0xffff);
        union { unsigned short u; __half h; } cv; cv.u = (unsigned short)w;
        zzA[p] = __half2float(cv.h);
    }
    __syncthreads();                         // HtF zero-init visible

#pragma unroll 1
    for (int t = 0; t < 128; t += 2) {
        // even: use zzA, reload zrA <- z(t+2), extract zrB(z(t+1)) -> zzB
        LSTM_STEP(t,     zrA, zzA, zrB, zzB, 0, 1);
        // odd:  use zzB, reload zrB <- z(t+3), extract zrA(z(t+2)) -> zzA
        LSTM_STEP(t + 1, zrB, zzB, zrA, zzA, 1, 0);
    }

    // ---- output projection: fp32 h -> bf16 staging tile -> MFMA ----
    for (int i = tid; i < 16 * LDH; i += 512) HtB[i] = (__bf16)0.f;
    __syncthreads();
#pragma unroll
    for (int hf = 0; hf < 2; ++hf)
        HtB[(4 * quad) * LDH + hf * 128 + col0] = (__bf16)hr[hf];
    __syncthreads();

    bf16x8 wo[8];
#pragma unroll
    for (int kt = 0; kt < 8; ++kt) {
        bf16x8 f;
#pragma unroll
        for (int j = 0; j < 8; ++j)
            f[j] = (__bf16)wout[(size_t)(kt * 32 + quad * 8 + j) * 128 + col0];
        wo[kt] = f;
    }
    f32x4 oa = {0.f, 0.f, 0.f, 0.f};
#pragma unroll
    for (int kt = 0; kt < 8; ++kt) {
        bf16x8 af = *(const bf16x8*)&HtB[l16 * LDH + kt * 32 + quad * 8];
        oa = mfma_bf16(af, wo[kt], oa);
    }
    out[(size_t)(rbblk * 4 + quad) * 128 + col0] = oa[0] + bout[col0];
}

extern "C" void kernel_launch(void* const* d_in, const int* in_sizes, int n_in,
                              void* d_out, int out_size, void* d_ws, size_t ws_size,
                              hipStream_t stream) {
    const float* x    = (const float*)d_in[0];
    const float* Wk   = (const float*)d_in[1];
    const float* bias = (const float*)d_in[2];
    const float* wout = (const float*)d_in[3];
    const float* bout = (const float*)d_in[4];
    float* out = (float*)d_out;

    __bf16*        WxF = (__bf16*)d_ws;                      // 512 KB
    unsigned char* WhF = (unsigned char*)d_ws + 524288;      // 256 KB (fp8 MX frags)
    uint2*         Zx  = (uint2*)((char*)d_ws + 2097152);    // 128 MB, 8 planes

    shuffle_w<<<160, 256, 0, stream>>>(Wk, WxF, WhF);
    xproj<<<4096, 256, 0, stream>>>(x, WxF, bias, Zx);
    lstm_rec<<<128, 512, 0, stream>>>(WhF, Zx, wout, bout, out);
}

// Round 9
// 417.277 us; speedup vs baseline: 1.5265x; 1.0368x over previous
//
#include <hip/hip_runtime.h>
#include <hip/hip_fp16.h>
#include <stdint.h>
#include <stddef.h>

// LSTM B=512,T=128,D=256,H=256,C=128, gates (i,j,f,o), FORGET_BIAS=1.
// R19 = R13's lstm_rec (proven 241us) + A-RESIDENT xproj:
//   R18 lesson: N-split grid re-read x 8x (512MB) and left each block
//   latency-exposed (620 MFMA-cyc vs ~300-cyc loads). xproj's true limits:
//   MFMA 13us, memory floor ~30us (64MB x read + 128MB Zx write).
//   New: one block = one 128-row M-tile (grid 512, 256 thr). Full 128x256
//   A-tile staged ONCE to LDS (67.5KB bf16, 2 blocks/CU), then all 8
//   N-planes computed inside the block: 8x A-reuse, x read exactly once,
//   zero barriers in the K/N loops, per-plane epilogue overlaps next plane.
//   Zx packing algebra bit-identical to R18 (harness-verified).

typedef __attribute__((ext_vector_type(8))) __bf16 bf16x8;
typedef __attribute__((ext_vector_type(4))) __bf16 bf16x4;
typedef __attribute__((ext_vector_type(4))) float  f32x4;
typedef __attribute__((ext_vector_type(8))) int    i32x8;

#define LDH   264          // bf16 row stride (out staging in lstm_rec)
#define LDF   272          // fp8 Ht row stride in bytes (256 + 16)
#define ZPS   2097152ull   // Zx plane stride in uint2 (32*128*8*64)
#define SONE  0x7F7F7F7F   // E8M0 unit scales (all blocks = 2^0)
#define LDA2  264          // xproj A-tile row stride in bf16 (256 + 8)

__device__ __forceinline__ f32x4 mfma_bf16(bf16x8 a, bf16x8 b, f32x4 c) {
    return __builtin_amdgcn_mfma_f32_16x16x32_bf16(a, b, c, 0, 0, 0);
}
#define EXP2(x) __builtin_amdgcn_exp2f(x)
#define RCP(x)  __builtin_amdgcn_rcpf(x)
#define L2E  1.442695040f
#define L2E2 2.885390082f

// ---------------- 1) weight shuffle ----------------
__global__ __launch_bounds__(256) void shuffle_w(const float* __restrict__ Wk,
                                                 __bf16* __restrict__ WxF,
                                                 unsigned char* __restrict__ WhF) {
    int id = blockIdx.x * 256 + threadIdx.x;
    if (id < 32768) {                                  // Wx part (rows 0..255)
        int lane = id & 63, kt = (id >> 6) & 7, nt = id >> 9;
        int quad = lane >> 4, l16 = lane & 15;
        const float* src = Wk + (size_t)(kt * 32 + quad * 8) * 1024 + nt * 16 + l16;
        __bf16* dst = WxF + ((size_t)(nt * 8 + kt) * 64 + lane) * 8;
#pragma unroll
        for (int j = 0; j < 8; ++j) dst[j] = (__bf16)src[(size_t)j * 1024];
    } else if (id < 40960) {                           // Wh part (rows 256..511)
        int i = id - 32768;
        int lane = i & 63, kt = (i >> 6) & 1, ng = i >> 7;
        int n = ng * 16 + (lane & 15);
        int kb = 256 + kt * 128 + (lane >> 4) * 32;
        int* dst = (int*)(WhF + (((size_t)ng * 2 + kt) * 64 + lane) * 32);
#pragma unroll
        for (int d = 0; d < 8; ++d) {
            float w0 = Wk[(size_t)(kb + 4 * d + 0) * 1024 + n];
            float w1 = Wk[(size_t)(kb + 4 * d + 1) * 1024 + n];
            float w2 = Wk[(size_t)(kb + 4 * d + 2) * 1024 + n];
            float w3 = Wk[(size_t)(kb + 4 * d + 3) * 1024 + n];
            int lo = __builtin_amdgcn_cvt_pk_fp8_f32(w0, w1, 0, false);
            dst[d]  = __builtin_amdgcn_cvt_pk_fp8_f32(w2, w3, lo, true);
        }
    }
}

// ---------------- 2) x-projection: A-resident 128-row M-tile ----------------
// Grid 512: bb = blk&31 (16 batch), tg = blk>>5 (8 t). M-row m: b=bb*16+(m&15),
// t=tg*8+(m>>4). Full A-tile (128x256 bf16) in LDS; loop p=0..7 N-planes
// inside. 4 waves: wm=w>>1 (64-row half), wn=w&1 (64-col half per plane).
__global__ __launch_bounds__(256, 2) void xproj(const float* __restrict__ x,
        const __bf16* __restrict__ WxF, const float* __restrict__ bias,
        uint2* __restrict__ Zx) {
    __shared__ __attribute__((aligned(16))) __bf16 As[128 * LDA2];
    const int tid = threadIdx.x, w = tid >> 6, lane = tid & 63;
    const int l16 = lane & 15, q = lane >> 4;
    const int bb = blockIdx.x & 31, tg = blockIdx.x >> 5;
    const int wm = w >> 1, wn = w & 1;

    // stage full A-tile: 128 rows x 256 k (fp32 -> bf16), x read ONCE.
#pragma unroll
    for (int i = 0; i < 32; ++i) {
        int s = tid + i * 256, row = s >> 6, f4 = s & 63;
        int b = bb * 16 + (row & 15), t_ = tg * 8 + (row >> 4);
        float4 v = *((const float4*)(x + (size_t)(b * 128 + t_) * 256) + f4);
        bf16x4 c4 = {(__bf16)v.x, (__bf16)v.y, (__bf16)v.z, (__bf16)v.w};
        *(bf16x4*)&As[row * LDA2 + f4 * 4] = c4;
    }
    __syncthreads();

#pragma unroll 1
    for (int p = 0; p < 8; ++p) {
        f32x4 acc[4][4];
#pragma unroll
        for (int tt = 0; tt < 4; ++tt)
#pragma unroll
            for (int nf = 0; nf < 4; ++nf) acc[tt][nf] = (f32x4){0.f, 0.f, 0.f, 0.f};

#pragma unroll
        for (int ks = 0; ks < 8; ++ks) {
            bf16x8 wf[4];
#pragma unroll
            for (int nf = 0; nf < 4; ++nf) {
                int ntF = p * 8 + wn * 4 + nf;
                wf[nf] = *(const bf16x8*)&WxF[(((size_t)ntF * 8 + ks) * 64 + lane) * 8];
            }
#pragma unroll
            for (int tt = 0; tt < 4; ++tt) {
                bf16x8 af = *(const bf16x8*)&As[(wm * 64 + tt * 16 + l16) * LDA2 + ks * 32 + q * 8];
#pragma unroll
                for (int nf = 0; nf < 4; ++nf)
                    acc[tt][nf] = mfma_bf16(af, wf[nf], acc[tt][nf]);
            }
        }

        // epilogue plane p: pack 4 b-rows (q*4+r) per lane into one uint2
        const float fb = (p == 4 || p == 5) ? 1.0f : 0.0f;
#pragma unroll
        for (int nf = 0; nf < 4; ++nf) {
            int cnt = wn * 4 + nf;
            float bb_ = bias[p * 128 + cnt * 16 + l16] + fb;
#pragma unroll
            for (int tt = 0; tt < 4; ++tt) {
                int t_ = tg * 8 + wm * 4 + tt;
                union { __half h[4]; uint2 u; } pk;
#pragma unroll
                for (int r = 0; r < 4; ++r) pk.h[r] = __float2half(acc[tt][nf][r] + bb_);
                Zx[(size_t)p * ZPS + ((size_t)(bb * 128 + t_) * 8 + cnt) * 64 + q * 16 + l16] = pk.u;
            }
        }
    }
}

// ---------------- 3) recurrent loop: 128 blocks x 4 batch rows ----------------
// BIT-IDENTICAL to R13/R15 (proven sound + 241us).
#define LSTM_STEP(TT, ZR, ZZU, ZRE, ZZE, RBUF, WBUF)                           \
    {                                                                          \
        i32x8 afr[2];                                                          \
        _Pragma("unroll")                                                      \
        for (int kt = 0; kt < 2; ++kt) {                                       \
            const uint4* ap = (const uint4*)&HtF[RBUF][l16 * LDF + kt * 128 + quad * 32]; \
            uint4 lo = ap[0], hi = ap[1];                                      \
            afr[kt] = (i32x8){(int)lo.x, (int)lo.y, (int)lo.z, (int)lo.w,      \
                              (int)hi.x, (int)hi.y, (int)hi.z, (int)hi.w};     \
        }                                                                      \
        f32x4 acc[8];                                                          \
        _Pragma("unroll")                                                      \
        for (int p = 0; p < 8; ++p) acc[p] = (f32x4){ZZU[p], 0.f, 0.f, 0.f};   \
        {                                                                      \
            int tl = ((TT) + 2 > 127) ? 127 : ((TT) + 2);                      \
            size_t zi = zi0 + (size_t)tl * 512;                                \
            _Pragma("unroll")                                                  \
            for (int p = 0; p < 8; ++p) ZR[p] = Zx[p * ZPS + zi];              \
        }                                                                      \
        __builtin_amdgcn_s_setprio(1);                                         \
        _Pragma("unroll")                                                      \
        for (int kt = 0; kt < 2; ++kt)                                         \
            _Pragma("unroll")                                                  \
            for (int p = 0; p < 8; ++p)                                        \
                acc[p] = __builtin_amdgcn_mfma_scale_f32_16x16x128_f8f6f4(     \
                    afr[kt], wreg[p * 2 + kt], acc[p], 0, 0, 0, SONE, 0, SONE);\
        __builtin_amdgcn_s_setprio(0);                                         \
        _Pragma("unroll")                                                      \
        for (int p = 0; p < 8; ++p) {                                          \
            unsigned w = (quad & 2) ? ZRE[p].y : ZRE[p].x;                     \
            w = (quad & 1) ? (w >> 16) : (w & 0xffff);                         \
            union { unsigned short u; __half h; } cv; cv.u = (unsigned short)w;\
            ZZE[p] = __half2float(cv.h);                                       \
        }                                                                      \
        unsigned char* ldsw = &HtF[WBUF][0];                                   \
        _Pragma("unroll")                                                      \
        for (int hf = 0; hf < 2; ++hf) {                                       \
            float iv = acc[0 + hf][0];                                         \
            float jv = acc[2 + hf][0];                                         \
            float fv = acc[4 + hf][0];                                         \
            float ov = acc[6 + hf][0];                                         \
            float si = RCP(1.f + EXP2(-L2E * iv));                             \
            float sf = RCP(1.f + EXP2(-L2E * fv));                             \
            float so = RCP(1.f + EXP2(-L2E * ov));                             \
            float tj = 2.f * RCP(1.f + EXP2(-L2E2 * jv)) - 1.f;                \
            float c = c_[hf] * sf + si * tj;                                   \
            c_[hf] = c;                                                        \
            float tc = 2.f * RCP(1.f + EXP2(-L2E2 * c)) - 1.f;                 \
            float h = tc * so;                                                 \
            hr[hf] = h;                                                        \
            unsigned pb = (unsigned)__builtin_amdgcn_cvt_pk_fp8_f32(h, h, 0, false); \
            ldsw[(4 * quad) * LDF + hf * 128 + col0] = (unsigned char)pb;      \
        }                                                                      \
        __syncthreads();   /* publish h(t+1) — architectural barrier */        \
    }

__global__ __launch_bounds__(512, 2) void lstm_rec(const unsigned char* __restrict__ WhF,
        const uint2* __restrict__ Zx, const float* __restrict__ wout,
        const float* __restrict__ bout, float* __restrict__ out) {
    __shared__ __attribute__((aligned(16))) unsigned char HtF[2][16 * LDF];
    __shared__ __attribute__((aligned(16))) __bf16 HtB[16 * LDH];   // out staging
    const int tid = threadIdx.x, wv = tid >> 6, lane = tid & 63;
    const int l16 = lane & 15, quad = lane >> 4;
    const int rbblk = blockIdx.x;            // batch rows 4*rbblk .. +3
    const int rb = rbblk >> 2, qb = rbblk & 3;

    // Wh MX B-frags: 16 x v8i32 = 128 regs (p = g*2+hf, kt128 = 0,1)
    i32x8 wreg[16];
#pragma unroll
    for (int p = 0; p < 8; ++p) {
        int ng = (p >> 1) * 16 + (p & 1) * 8 + wv;   // cols g*256+hf*128+wv*16+l16
#pragma unroll
        for (int kt = 0; kt < 2; ++kt) {
            const uint4* wp = (const uint4*)(WhF + (((size_t)ng * 2 + kt) * 64 + lane) * 32);
            uint4 lo = wp[0], hi = wp[1];
            wreg[p * 2 + kt] = (i32x8){(int)lo.x, (int)lo.y, (int)lo.z, (int)lo.w,
                                       (int)hi.x, (int)hi.y, (int)hi.z, (int)hi.w};
        }
    }
    for (int i = tid; i < (16 * LDF * 2) / 4; i += 512) ((uint*)HtF[0])[i] = 0u;

    const int col0 = wv * 16 + l16;
    float c_[2] = {0.f, 0.f};
    float hr[2] = {0.f, 0.f};
    const size_t zi0 = ((size_t)rb * 1024 + wv) * 64 + qb * 16 + l16;

    // raw ping-pong (uint2) + extracted-float ping-pong
    uint2 zrA[8], zrB[8];
    float zzA[8], zzB[8];
#pragma unroll
    for (int p = 0; p < 8; ++p) zrA[p] = Zx[p * ZPS + zi0];
#pragma unroll
    for (int p = 0; p < 8; ++p) zrB[p] = Zx[p * ZPS + zi0 + 512];
#pragma unroll
    for (int p = 0; p < 8; ++p) {            // pre-extract z(0) -> zzA
        unsigned w = (quad & 2) ? zrA[p].y : zrA[p].x;
        w = (quad & 1) ? (w >> 16) : (w & 0xffff);
        union { unsigned short u; __half h; } cv; cv.u = (unsigned short)w;
        zzA[p] = __half2float(cv.h);
    }
    __syncthreads();                         // HtF zero-init visible

#pragma unroll 1
    for (int t = 0; t < 128; t += 2) {
        // even: use zzA, reload zrA <- z(t+2), extract zrB(z(t+1)) -> zzB
        LSTM_STEP(t,     zrA, zzA, zrB, zzB, 0, 1);
        // odd:  use zzB, reload zrB <- z(t+3), extract zrA(z(t+2)) -> zzA
        LSTM_STEP(t + 1, zrB, zzB, zrA, zzA, 1, 0);
    }

    // ---- output projection: fp32 h -> bf16 staging tile -> MFMA ----
    for (int i = tid; i < 16 * LDH; i += 512) HtB[i] = (__bf16)0.f;
    __syncthreads();
#pragma unroll
    for (int hf = 0; hf < 2; ++hf)
        HtB[(4 * quad) * LDH + hf * 128 + col0] = (__bf16)hr[hf];
    __syncthreads();

    bf16x8 wo[8];
#pragma unroll
    for (int kt = 0; kt < 8; ++kt) {
        bf16x8 f;
#pragma unroll
        for (int j = 0; j < 8; ++j)
            f[j] = (__bf16)wout[(size_t)(kt * 32 + quad * 8 + j) * 128 + col0];
        wo[kt] = f;
    }
    f32x4 oa = {0.f, 0.f, 0.f, 0.f};
#pragma unroll
    for (int kt = 0; kt < 8; ++kt) {
        bf16x8 af = *(const bf16x8*)&HtB[l16 * LDH + kt * 32 + quad * 8];
        oa = mfma_bf16(af, wo[kt], oa);
    }
    out[(size_t)(rbblk * 4 + quad) * 128 + col0] = oa[0] + bout[col0];
}

extern "C" void kernel_launch(void* const* d_in, const int* in_sizes, int n_in,
                              void* d_out, int out_size, void* d_ws, size_t ws_size,
                              hipStream_t stream) {
    const float* x    = (const float*)d_in[0];
    const float* Wk   = (const float*)d_in[1];
    const float* bias = (const float*)d_in[2];
    const float* wout = (const float*)d_in[3];
    const float* bout = (const float*)d_in[4];
    float* out = (float*)d_out;

    __bf16*        WxF = (__bf16*)d_ws;                      // 512 KB
    unsigned char* WhF = (unsigned char*)d_ws + 524288;      // 256 KB (fp8 MX frags)
    uint2*         Zx  = (uint2*)((char*)d_ws + 2097152);    // 128 MB, 8 planes

    shuffle_w<<<160, 256, 0, stream>>>(Wk, WxF, WhF);
    xproj<<<512, 256, 0, stream>>>(x, WxF, bias, Zx);
    lstm_rec<<<128, 512, 0, stream>>>(WhF, Zx, wout, bout, out);
}